// Round 2
// baseline (113.970 us; speedup 1.0000x reference)
//
#include <hip/hip_runtime.h>
#include <hip/hip_fp8.h>
#include <math.h>

// ContrastiveLoss — x (8,128,16,8,8) fp32 (4 MB).
// feats[n,f] = x[b*131072 + f*1024 + r], n=(b<<10)|r, N=8192, F=128.
// loss = 10 + ln( sum_{i!=j} exp(10*dot(x̂_i,x̂_j) - 10) )   (unit rows => s<=10)
//
// Round 11: fix R10's spill regression. R10's dual instantiation
// (gram_tiles<9> ?: gram_tiles<8>) collapsed the allocator to 64 VGPR and
// spilled the pipeline (WRITE_SIZE 43.8 MB/dispatch = scratch). This round:
//  * SINGLE instantiation, uniform NT=3, 2752 blocks (divisor of 8256).
//    Per-CU makespan bound: max 33 tile-units vs avg 32.25 (+2.3%), vs
//    R9's NT=6/1376 max 36 (+11.6%). Same proven pipeline structure
//    (B triple-buffered, 2-deep prefetch, A reload on row change).
//  * Keep fused final reduction (counter + last-block f64 reduce; passed
//    bit-exact in R10) and closed-form triangular decode.
//
// fp8 swizzled layout (verified R7/R8, absmax 0): row-group rg=n>>4 (16 rows,
// 2KB). 16B chunk (t8*64 + q*16 + r) holds bytes[half*8+j] =
// x̂[row r][k = t8*64 + half*32 + q*8 + j] — lane q*16+r's A/B fragments for
// k-steps 2*t8 (low 8B) / 2*t8+1 (high 8B) of mfma_f32_16x16x32_fp8_fp8.
// C/D layout dtype-independent: col=lane&15, row=(lane>>4)*4+reg.
//
// ws: partials float[2752] @0; counter u32 @16384; Xs fp8[8192*128] @131072.

#define NTILE 8256   // 128*129/2 upper-triangle 64x64 tiles
#define NT_PB 3      // tiles per block (uniform)
#define NPBLK 2752   // 8256 / 3

typedef __attribute__((ext_vector_type(4))) float f32x4;

#if __has_builtin(__builtin_amdgcn_exp2f)
#define EXP2F(x) __builtin_amdgcn_exp2f(x)
#else
#define EXP2F(x) exp2f(x)
#endif

__device__ inline unsigned int pk_fp8(float f0, float f1, float f2, float f3) {
#if __has_builtin(__builtin_amdgcn_cvt_pk_fp8_f32)
    unsigned int r = 0;
    r = __builtin_amdgcn_cvt_pk_fp8_f32(f0, f1, r, false);  // bytes 0,1
    r = __builtin_amdgcn_cvt_pk_fp8_f32(f2, f3, r, true);   // bytes 2,3
    return r;
#else
    union { unsigned char b[4]; unsigned int u; } v;
    v.b[0] = __hip_fp8_e4m3(f0).__x; v.b[1] = __hip_fp8_e4m3(f1).__x;
    v.b[2] = __hip_fp8_e4m3(f2).__x; v.b[3] = __hip_fp8_e4m3(f3).__x;
    return v.u;
#endif
}

// ---------------------------------------------------------------------------
// Kernel 1: normalize + fp8 swizzle. Block = 32 rows (2 row-groups).
// Phase 1: coalesced read of x (each element once) into LDS (pad 33).
// Phase 2: one 16B output chunk per thread (HW packed fp8 convert).
// Also zero-inits the gram completion counter (ws is poisoned between runs).
// ---------------------------------------------------------------------------
__global__ __launch_bounds__(256)
void normalize_kernel(const float* __restrict__ x, unsigned char* __restrict__ Xs,
                      unsigned int* __restrict__ counter) {
    if (blockIdx.x == 0 && threadIdx.x == 0) counter[0] = 0u;
    __shared__ float ldsf[128][33];
    __shared__ float ssred[8][32];
    __shared__ float invs[32];
    const int tid = threadIdx.x;
    const int b  = blockIdx.x >> 5;
    const int r0 = (blockIdx.x & 31) * 32;
    const int rl = tid & 31, fp = tid >> 5;       // row-in-block, f-slot
    const float* px = x + b * 131072 + r0 + rl;
    float ss = 0.f;
#pragma unroll
    for (int j = 0; j < 16; ++j) {
        int f = fp * 16 + j;
        float v = px[f * 1024];
        ldsf[f][rl] = v;
        ss = fmaf(v, v, ss);
    }
    ssred[fp][rl] = ss;
    __syncthreads();
    if (tid < 32) {
        float s = 0.f;
#pragma unroll
        for (int k = 0; k < 8; ++k) s += ssred[k][tid];
        invs[tid] = 1.0f / fmaxf(sqrtf(s), 1e-12f);
    }
    __syncthreads();
    {   // one 16B chunk per thread, consecutive tid -> consecutive chunks
        const int c   = tid;
        const int rgl = c >> 7;                   // local row-group 0..1
        const int cc  = c & 127;                  // chunk within row-group
        const int t8  = (cc >> 6) & 1, q = (cc >> 4) & 3, r = cc & 15;
        const int row = rgl * 16 + r;             // local row 0..31
        const float inv = invs[row];
        union { unsigned int w[4]; int4 v; } u;
#pragma unroll
        for (int half = 0; half < 2; ++half) {
            const int k0 = t8 * 64 + half * 32 + q * 8;
            u.w[half * 2 + 0] = pk_fp8(ldsf[k0 + 0][row] * inv, ldsf[k0 + 1][row] * inv,
                                       ldsf[k0 + 2][row] * inv, ldsf[k0 + 3][row] * inv);
            u.w[half * 2 + 1] = pk_fp8(ldsf[k0 + 4][row] * inv, ldsf[k0 + 5][row] * inv,
                                       ldsf[k0 + 6][row] * inv, ldsf[k0 + 7][row] * inv);
        }
        const int rgg = blockIdx.x * 2 + rgl;     // global row-group
        ((int4*)Xs)[rgg * 128 + cc] = u.v;
    }
}

// ---------------------------------------------------------------------------
// Gram tile run: NT contiguous upper-triangle tiles starting at linear index
// tstart. Closed-form (I,J) decode; B triple-buffered with 2-deep prefetch;
// A register-resident per row-run. Single instantiation (NT=3) — R10's dual
// instantiation spilled the pipeline to scratch.
// ---------------------------------------------------------------------------
template <int NT>
__device__ __forceinline__ float gram_tiles(const int4* __restrict__ Xs,
                                            int tstart, int lane, int w) {
    const int ga = (w & 1) * 2;                  // A rg offset within tile
    const int gb = (w >> 1) * 2;                 // B rg offset within tile
    const int quad = lane >> 4, colL = lane & 15;
    const float C = 14.426950408889634f;         // 10*log2(e)

    // closed-form decode of first tile: tiles_before(i) = i*(257-i)/2
    int Is[NT], Js[NT];
    {
        const int t = tstart;
        int i = (int)((257.0 - sqrt(66049.0 - 8.0 * (double)t)) * 0.5);
        if (i < 0) i = 0;
        while ((((i + 1) * (256 - i)) >> 1) <= t) ++i;   // tb(i+1) <= t
        while (((i * (257 - i)) >> 1) > t) --i;          // tb(i)   >  t
        int j = i + (t - ((i * (257 - i)) >> 1));
#pragma unroll
        for (int s = 0; s < NT; ++s) {
            Is[s] = i; Js[s] = j;
            if (++j == 128) { ++i; j = i; }
        }
    }

    // A fragments for the first row of the run
    int4 av[2][2];
    int IcurA = Is[0];
#pragma unroll
    for (int g = 0; g < 2; ++g)
#pragma unroll
        for (int t8 = 0; t8 < 2; ++t8)
            av[g][t8] = Xs[(Is[0] * 4 + ga + g) * 128 + t8 * 64 + lane];

    // B triple buffer, prefetch tiles 0 and 1
    int4 bv[3][2][2];
#pragma unroll
    for (int pf = 0; pf < 2; ++pf)
#pragma unroll
        for (int g = 0; g < 2; ++g)
#pragma unroll
            for (int t8 = 0; t8 < 2; ++t8)
                bv[pf][g][t8] = Xs[(Js[pf] * 4 + gb + g) * 128 + t8 * 64 + lane];

    float wsum = 0.f;
#pragma unroll
    for (int s = 0; s < NT; ++s) {
        // 2-deep prefetch of tile s+2's B fragments
        if (s + 2 < NT) {
#pragma unroll
            for (int g = 0; g < 2; ++g)
#pragma unroll
                for (int t8 = 0; t8 < 2; ++t8)
                    bv[(s + 2) % 3][g][t8] =
                        Xs[(Js[s + 2] * 4 + gb + g) * 128 + t8 * 64 + lane];
        }
        // A reload only when the run crosses a row boundary
        if (Is[s] != IcurA) {
#pragma unroll
            for (int g = 0; g < 2; ++g)
#pragma unroll
                for (int t8 = 0; t8 < 2; ++t8)
                    av[g][t8] = Xs[(Is[s] * 4 + ga + g) * 128 + t8 * 64 + lane];
            IcurA = Is[s];
        }

        f32x4 acc[2][2];
#pragma unroll
        for (int i = 0; i < 2; ++i)
#pragma unroll
            for (int j = 0; j < 2; ++j) acc[i][j] = (f32x4){0.f, 0.f, 0.f, 0.f};
#pragma unroll
        for (int t = 0; t < 4; ++t) {            // K-steps of 32
            long aL[2], bL[2];
#pragma unroll
            for (int g = 0; g < 2; ++g) {
                aL[g] = ((const long*)&av[g][t >> 1])[t & 1];
                bL[g] = ((const long*)&bv[s % 3][g][t >> 1])[t & 1];
            }
#pragma unroll
            for (int i = 0; i < 2; ++i)
#pragma unroll
                for (int j = 0; j < 2; ++j)
                    acc[i][j] = __builtin_amdgcn_mfma_f32_16x16x32_fp8_fp8(
                        aL[i], bL[j], acc[i][j], 0, 0, 0);
        }

        // C/D: col=lane&15, row=(lane>>4)*4+reg (dtype-independent, verified)
        const bool diagT = (Is[s] == Js[s]);
        float l0 = 0.f, l1 = 0.f;                // 2 accumulators: shorter chain
#pragma unroll
        for (int i = 0; i < 2; ++i) {
            const int rbase = (ga + i) * 16 + quad * 4;   // row within tile
            float lacc = 0.f;
#pragma unroll
            for (int j = 0; j < 2; ++j) {
                const int cbase = (gb + j) * 16 + colL;   // col within tile
#pragma unroll
                for (int g = 0; g < 4; ++g) {
                    if (diagT && (rbase + g == cbase)) continue;
                    lacc += EXP2F(fmaf(C, acc[i][j][g], -C));
                }
            }
            if (i == 0) l0 = lacc; else l1 = lacc;
        }
        const float lsum = l0 + l1;
        wsum += diagT ? lsum : 2.0f * lsum;      // symmetry weight
    }
    return wsum;
}

// ---------------------------------------------------------------------------
// Kernel 2: persistent gram + fused final reduction. 2752 blocks x 3 tiles,
// uniform — per-CU work bounded at 33 vs 32.25 avg tile-units. Per-block
// partial -> counter; the LAST block performs the same fixed-order f64
// reduction the old final_kernel did (deterministic).
// ---------------------------------------------------------------------------
__global__ __launch_bounds__(256, 4)
void gram_lse_kernel(const int4* __restrict__ Xs, float* __restrict__ partials,
                     unsigned int* __restrict__ counter, float* __restrict__ out) {
    const int bk = blockIdx.x;
    const int tid = threadIdx.x;
    const int lane = tid & 63, w = tid >> 6;

    float wsum = gram_tiles<NT_PB>(Xs, bk * NT_PB, lane, w);

#pragma unroll
    for (int o = 32; o > 0; o >>= 1) wsum += __shfl_down(wsum, o, 64);
    __shared__ float red[4];
    __shared__ bool last;
    if (lane == 0) red[w] = wsum;
    __syncthreads();
    if (tid == 0) {
        partials[bk] = red[0] + red[1] + red[2] + red[3];
        __threadfence();                          // publish partial (cross-XCD)
        last = (atomicAdd(counter, 1u) == NPBLK - 1);
    }
    __syncthreads();
    if (last) {
        __threadfence();                          // acquire all partials
        double s = 0.0;
        for (int i = tid; i < NPBLK; i += 256) s += (double)partials[i];
#pragma unroll
        for (int o = 32; o > 0; o >>= 1) s += __shfl_down(s, o, 64);
        __shared__ double dred[4];
        if (lane == 0) dred[w] = s;
        __syncthreads();
        if (tid == 0)
            out[0] = (float)(10.0 + log(dred[0] + dred[1] + dred[2] + dred[3]));
    }
}

extern "C" void kernel_launch(void* const* d_in, const int* in_sizes, int n_in,
                              void* d_out, int out_size, void* d_ws, size_t ws_size,
                              hipStream_t stream) {
    const float* x = (const float*)d_in[0];
    float* out = (float*)d_out;
    float* partials = (float*)d_ws;                           // 2752 floats @0
    unsigned int* counter = (unsigned int*)((char*)d_ws + 16384);
    unsigned char* Xs = (unsigned char*)d_ws + 131072;        // 1MB fp8 X̂

    normalize_kernel<<<256, 256, 0, stream>>>(x, Xs, counter);
    gram_lse_kernel<<<NPBLK, 256, 0, stream>>>((const int4*)Xs, partials, counter, out);
}

// Round 3
// 71.697 us; speedup vs baseline: 1.5896x; 1.5896x over previous
//
#include <hip/hip_runtime.h>
#include <hip/hip_fp8.h>
#include <math.h>

// ContrastiveLoss — x (8,128,16,8,8) fp32 (4 MB).
// feats[n,f] = x[b*131072 + f*1024 + r], n=(b<<10)|r, N=8192, F=128.
// loss = 10 + ln( sum_{i!=j} exp(10*dot(x̂_i,x̂_j) - 10) )   (unit rows => s<=10)
//
// Round 12: RE-ANCHOR. Byte-for-byte revert to the verified 72.4 µs R9 kernel.
// R10 (dual-NT fusion) and R11 (NT=3 fusion) both regressed (109.5 / 114.0 µs):
// R10 spilled the pipeline (VGPR 64, 43.8 MB scratch writes); R11 allocated
// only 44 VGPR (pipeline gone, 85% of cycles idle on load latency). Both
// bundled {fused final reduction, NT change, decode change} — attribution
// impossible. This round isolates: exact R9 → expect 72.4 µs again, and
// (hopefully) clean gram counters in the top-5 for the next single-variable
// experiment.
//
// R9 structure: explicit software-pipelined fp8 gram. 1376 blocks x 6
// contiguous tiles; per-block tile list precomputed; B fragments TRIPLE-
// buffered with 2-deep prefetch; A register-resident per row-run;
// __launch_bounds__(256,4) (~128 VGPR) so the pipeline buffers actually stay
// in registers ((256,6)'s ~84-VGPR budget blocked compiler pipelining).
//
// fp8 swizzled layout (verified R7/R8, absmax 0): row-group rg=n>>4 (16 rows,
// 2KB). 16B chunk (t8*64 + q*16 + r) holds bytes[half*8+j] =
// x̂[row r][k = t8*64 + half*32 + q*8 + j] — lane q*16+r's A/B fragments for
// k-steps 2*t8 (low 8B) / 2*t8+1 (high 8B) of mfma_f32_16x16x32_fp8_fp8.
// C/D layout dtype-independent: col=lane&15, row=(lane>>4)*4+reg.
//
// ws: partials float[1376] @0; Xs fp8[8192*128] @131072 (1MB).

#define NTILE 8256   // 128*129/2 upper-triangle 64x64 tiles
#define NPBLK 1376   // 8256 / 6 tiles per block

typedef __attribute__((ext_vector_type(4))) float f32x4;

#if __has_builtin(__builtin_amdgcn_exp2f)
#define EXP2F(x) __builtin_amdgcn_exp2f(x)
#else
#define EXP2F(x) exp2f(x)
#endif

__device__ inline unsigned int pk_fp8(float f0, float f1, float f2, float f3) {
#if __has_builtin(__builtin_amdgcn_cvt_pk_fp8_f32)
    unsigned int r = 0;
    r = __builtin_amdgcn_cvt_pk_fp8_f32(f0, f1, r, false);  // bytes 0,1
    r = __builtin_amdgcn_cvt_pk_fp8_f32(f2, f3, r, true);   // bytes 2,3
    return r;
#else
    union { unsigned char b[4]; unsigned int u; } v;
    v.b[0] = __hip_fp8_e4m3(f0).__x; v.b[1] = __hip_fp8_e4m3(f1).__x;
    v.b[2] = __hip_fp8_e4m3(f2).__x; v.b[3] = __hip_fp8_e4m3(f3).__x;
    return v.u;
#endif
}

// ---------------------------------------------------------------------------
// Kernel 1: normalize + fp8 swizzle. Block = 32 rows (2 row-groups).
// Phase 1: coalesced read of x (each element once) into LDS (pad 33).
// Phase 2: one 16B output chunk per thread (HW packed fp8 convert).
// ---------------------------------------------------------------------------
__global__ __launch_bounds__(256)
void normalize_kernel(const float* __restrict__ x, unsigned char* __restrict__ Xs) {
    __shared__ float ldsf[128][33];
    __shared__ float ssred[8][32];
    __shared__ float invs[32];
    const int tid = threadIdx.x;
    const int b  = blockIdx.x >> 5;
    const int r0 = (blockIdx.x & 31) * 32;
    const int rl = tid & 31, fp = tid >> 5;       // row-in-block, f-slot
    const float* px = x + b * 131072 + r0 + rl;
    float ss = 0.f;
#pragma unroll
    for (int j = 0; j < 16; ++j) {
        int f = fp * 16 + j;
        float v = px[f * 1024];
        ldsf[f][rl] = v;
        ss = fmaf(v, v, ss);
    }
    ssred[fp][rl] = ss;
    __syncthreads();
    if (tid < 32) {
        float s = 0.f;
#pragma unroll
        for (int k = 0; k < 8; ++k) s += ssred[k][tid];
        invs[tid] = 1.0f / fmaxf(sqrtf(s), 1e-12f);
    }
    __syncthreads();
    {   // one 16B chunk per thread, consecutive tid -> consecutive chunks
        const int c   = tid;
        const int rgl = c >> 7;                   // local row-group 0..1
        const int cc  = c & 127;                  // chunk within row-group
        const int t8  = (cc >> 6) & 1, q = (cc >> 4) & 3, r = cc & 15;
        const int row = rgl * 16 + r;             // local row 0..31
        const float inv = invs[row];
        union { unsigned int w[4]; int4 v; } u;
#pragma unroll
        for (int half = 0; half < 2; ++half) {
            const int k0 = t8 * 64 + half * 32 + q * 8;
            u.w[half * 2 + 0] = pk_fp8(ldsf[k0 + 0][row] * inv, ldsf[k0 + 1][row] * inv,
                                       ldsf[k0 + 2][row] * inv, ldsf[k0 + 3][row] * inv);
            u.w[half * 2 + 1] = pk_fp8(ldsf[k0 + 4][row] * inv, ldsf[k0 + 5][row] * inv,
                                       ldsf[k0 + 6][row] * inv, ldsf[k0 + 7][row] * inv);
        }
        const int rgg = blockIdx.x * 2 + rgl;     // global row-group
        ((int4*)Xs)[rgg * 128 + cc] = u.v;
    }
}

// ---------------------------------------------------------------------------
// Kernel 2: software-pipelined persistent gram. Block k: tiles 6k..6k+5.
// Wave w: A rgs (w&1)*2..+1, B rgs (w>>1)*2..+1 of each 64x64 tile.
// B triple-buffered, 2-deep prefetch; A reloaded only on row change.
// No barriers in the loop; per-thread wsum; one block reduce at the end.
// ---------------------------------------------------------------------------
__global__ __launch_bounds__(256, 4)
void gram_lse_kernel(const int4* __restrict__ Xs, float* __restrict__ partials) {
    const int bk = blockIdx.x;
    const int tid = threadIdx.x;
    const int lane = tid & 63, w = tid >> 6;
    const int ga = (w & 1) * 2;                  // A rg offset within tile
    const int gb = (w >> 1) * 2;                 // B rg offset within tile
    const int quad = lane >> 4, colL = lane & 15;
    const float C = 14.426950408889634f;         // 10*log2(e)

    // decode first tile of the run, then the whole 6-tile list
    int L = bk * 6, I0 = 0;
    while (L >= 128 - I0) { L -= 128 - I0; ++I0; }
    int Is[6], Js[6];
    {
        int ii = I0, jj = I0 + L;
#pragma unroll
        for (int s = 0; s < 6; ++s) {
            Is[s] = ii; Js[s] = jj;
            if (++jj == 128) { ++ii; jj = ii; }
        }
    }

    // A fragments for the first row of the run
    int4 av[2][2];
    int IcurA = Is[0];
#pragma unroll
    for (int g = 0; g < 2; ++g)
#pragma unroll
        for (int t8 = 0; t8 < 2; ++t8)
            av[g][t8] = Xs[(Is[0] * 4 + ga + g) * 128 + t8 * 64 + lane];

    // B triple buffer, prefetch tiles 0 and 1
    int4 bv[3][2][2];
#pragma unroll
    for (int pf = 0; pf < 2; ++pf)
#pragma unroll
        for (int g = 0; g < 2; ++g)
#pragma unroll
            for (int t8 = 0; t8 < 2; ++t8)
                bv[pf][g][t8] = Xs[(Js[pf] * 4 + gb + g) * 128 + t8 * 64 + lane];

    float wsum = 0.f;
#pragma unroll
    for (int s = 0; s < 6; ++s) {
        // 2-deep prefetch of tile s+2's B fragments
        if (s + 2 < 6) {
#pragma unroll
            for (int g = 0; g < 2; ++g)
#pragma unroll
                for (int t8 = 0; t8 < 2; ++t8)
                    bv[(s + 2) % 3][g][t8] =
                        Xs[(Js[s + 2] * 4 + gb + g) * 128 + t8 * 64 + lane];
        }
        // A reload only when the run crosses a row boundary (~1x per block)
        if (Is[s] != IcurA) {
#pragma unroll
            for (int g = 0; g < 2; ++g)
#pragma unroll
                for (int t8 = 0; t8 < 2; ++t8)
                    av[g][t8] = Xs[(Is[s] * 4 + ga + g) * 128 + t8 * 64 + lane];
            IcurA = Is[s];
        }

        f32x4 acc[2][2];
#pragma unroll
        for (int i = 0; i < 2; ++i)
#pragma unroll
            for (int j = 0; j < 2; ++j) acc[i][j] = (f32x4){0.f, 0.f, 0.f, 0.f};
#pragma unroll
        for (int t = 0; t < 4; ++t) {            // K-steps of 32
            long aL[2], bL[2];
#pragma unroll
            for (int g = 0; g < 2; ++g) {
                aL[g] = ((const long*)&av[g][t >> 1])[t & 1];
                bL[g] = ((const long*)&bv[s % 3][g][t >> 1])[t & 1];
            }
#pragma unroll
            for (int i = 0; i < 2; ++i)
#pragma unroll
                for (int j = 0; j < 2; ++j)
                    acc[i][j] = __builtin_amdgcn_mfma_f32_16x16x32_fp8_fp8(
                        aL[i], bL[j], acc[i][j], 0, 0, 0);
        }

        // C/D: col=lane&15, row=(lane>>4)*4+reg (dtype-independent, verified)
        const bool diagT = (Is[s] == Js[s]);
        float lsum = 0.f;
#pragma unroll
        for (int i = 0; i < 2; ++i) {
            const int rbase = (ga + i) * 16 + quad * 4;   // row within tile
#pragma unroll
            for (int j = 0; j < 2; ++j) {
                const int cbase = (gb + j) * 16 + colL;   // col within tile
#pragma unroll
                for (int g = 0; g < 4; ++g) {
                    if (diagT && (rbase + g == cbase)) continue;
                    lsum += EXP2F(fmaf(C, acc[i][j][g], -C));
                }
            }
        }
        wsum += diagT ? lsum : 2.0f * lsum;      // symmetry weight
    }

#pragma unroll
    for (int o = 32; o > 0; o >>= 1) wsum += __shfl_down(wsum, o, 64);
    __shared__ float red[4];
    if (lane == 0) red[w] = wsum;
    __syncthreads();
    if (tid == 0) partials[bk] = red[0] + red[1] + red[2] + red[3];
}

// ---------------------------------------------------------------------------
// Kernel 3: out = 10 + ln(sum of 1376 partials), f64 accumulation.
// ---------------------------------------------------------------------------
__global__ __launch_bounds__(256)
void final_kernel(const float* __restrict__ partials, float* __restrict__ out) {
    double s = 0.0;
    for (int i = threadIdx.x; i < NPBLK; i += 256) s += (double)partials[i];
#pragma unroll
    for (int o = 32; o > 0; o >>= 1) s += __shfl_down(s, o, 64);
    __shared__ double red[4];
    if ((threadIdx.x & 63) == 0) red[threadIdx.x >> 6] = s;
    __syncthreads();
    if (threadIdx.x == 0)
        out[0] = (float)(10.0 + log(red[0] + red[1] + red[2] + red[3]));
}

extern "C" void kernel_launch(void* const* d_in, const int* in_sizes, int n_in,
                              void* d_out, int out_size, void* d_ws, size_t ws_size,
                              hipStream_t stream) {
    const float* x = (const float*)d_in[0];
    float* out = (float*)d_out;
    float* partials = (float*)d_ws;                         // 1376 floats
    unsigned char* Xs = (unsigned char*)d_ws + 131072;      // 1MB fp8 X̂

    normalize_kernel<<<256, 256, 0, stream>>>(x, Xs);
    gram_lse_kernel<<<NPBLK, 256, 0, stream>>>((const int4*)Xs, partials);
    final_kernel<<<1, 256, 0, stream>>>(partials, out);
}